// Round 1
// baseline (356.815 us; speedup 1.0000x reference)
//
#include <hip/hip_runtime.h>
#include <hip/hip_bf16.h>

#define S_LEN 2048
#define D_DIM 64
#define QBLK  32
#define NWAVE 4
#define WCOLS (S_LEN / NWAVE)   // 512 columns per wave

typedef __attribute__((ext_vector_type(4))) float f32x4;
typedef __attribute__((ext_vector_type(8))) short s16x8;

union FU { float f; unsigned int u; };

__device__ __forceinline__ float bf2f(unsigned short h){
    FU x; x.u = ((unsigned int)h) << 16; return x.f;
}
__device__ __forceinline__ unsigned short f2bf(float f){
    FU x; x.f = f;
    unsigned int r = x.u + 0x7fffu + ((x.u >> 16) & 1u);
    return (unsigned short)(r >> 16);
}
// XOR-swizzle 16-elem blocks by (row>>2)&3 -> bank-uniform LDS access patterns
__device__ __forceinline__ int swz(int row, int col){
    return col ^ ((row & 12) << 2);
}

__global__ __launch_bounds__(256, 1)
void sdpa_kernel(const float* __restrict__ Q, const float* __restrict__ K,
                 const float* __restrict__ V, float* __restrict__ Out,
                 float* __restrict__ Score)
{
    __shared__ unsigned short sc[QBLK][S_LEN];   // 131072 B, bf16 scores / exp
    __shared__ float wred[NWAVE][QBLK];
    __shared__ float mrow[QBLK];
    __shared__ float invl[QBLK];

    const int bh    = blockIdx.y;
    const int qbase = blockIdx.x * QBLK;
    const int tid   = threadIdx.x;
    const int w     = tid >> 6;
    const int l     = tid & 63;
    const int lg    = l >> 4;      // lane group 0..3
    const int ln    = l & 15;

    const float scale = 0.125f;    // 1/sqrt(64)

    const size_t hbase = (size_t)bh * S_LEN * D_DIM;
    const float* Qh = Q + hbase;
    const float* Kh = K + hbase;
    const float* Vh = V + hbase;

    // ---------------- load Q fragments (A operand): 2 row-tiles x 2 K-steps
    s16x8 qf[2][2];
    #pragma unroll
    for (int t = 0; t < 2; ++t){
        const float* qrow = Qh + (size_t)(qbase + t*16 + ln) * D_DIM;
        #pragma unroll
        for (int s = 0; s < 2; ++s){
            const f32x4* p = (const f32x4*)(qrow + s*32 + lg*8);
            f32x4 a = p[0], b = p[1];
            s16x8 f;
            f[0]=(short)f2bf(a[0]); f[1]=(short)f2bf(a[1]); f[2]=(short)f2bf(a[2]); f[3]=(short)f2bf(a[3]);
            f[4]=(short)f2bf(b[0]); f[5]=(short)f2bf(b[1]); f[6]=(short)f2bf(b[2]); f[7]=(short)f2bf(b[3]);
            qf[t][s] = f;
        }
    }

    // ---------------- pass 1: S = (Q K^T)*scale -> bf16 LDS, track row max
    float mloc[8];
    #pragma unroll
    for (int i = 0; i < 8; ++i) mloc[i] = -1e30f;

    const int cw = w * WCOLS;
    #pragma unroll 2
    for (int i = 0; i < 32; ++i){
        const int nb = cw + i*16;
        s16x8 kf[2];
        const float* krow = Kh + (size_t)(nb + ln) * D_DIM;
        #pragma unroll
        for (int s = 0; s < 2; ++s){
            const f32x4* p = (const f32x4*)(krow + s*32 + lg*8);
            f32x4 a = p[0], b = p[1];
            s16x8 f;
            f[0]=(short)f2bf(a[0]); f[1]=(short)f2bf(a[1]); f[2]=(short)f2bf(a[2]); f[3]=(short)f2bf(a[3]);
            f[4]=(short)f2bf(b[0]); f[5]=(short)f2bf(b[1]); f[6]=(short)f2bf(b[2]); f[7]=(short)f2bf(b[3]);
            kf[s] = f;
        }
        #pragma unroll
        for (int t = 0; t < 2; ++t){
            f32x4 acc = {0.f, 0.f, 0.f, 0.f};
            acc = __builtin_amdgcn_mfma_f32_16x16x32_bf16(qf[t][0], kf[0], acc, 0, 0, 0);
            acc = __builtin_amdgcn_mfma_f32_16x16x32_bf16(qf[t][1], kf[1], acc, 0, 0, 0);
            #pragma unroll
            for (int r = 0; r < 4; ++r){
                const float v = acc[r] * scale;
                mloc[t*4 + r] = fmaxf(mloc[t*4 + r], v);
                const int row = t*16 + lg*4 + r;
                sc[row][swz(row, nb + ln)] = f2bf(v);
            }
        }
    }

    // row max: reduce across the 16 lanes that share a row set
    #pragma unroll
    for (int m = 1; m < 16; m <<= 1){
        #pragma unroll
        for (int i = 0; i < 8; ++i) mloc[i] = fmaxf(mloc[i], __shfl_xor(mloc[i], m, 64));
    }
    if (ln == 0){
        #pragma unroll
        for (int t = 0; t < 2; ++t)
            #pragma unroll
            for (int r = 0; r < 4; ++r)
                wred[w][t*16 + lg*4 + r] = mloc[t*4 + r];
    }
    __syncthreads();
    if (tid < QBLK){
        mrow[tid] = fmaxf(fmaxf(wred[0][tid], wred[1][tid]),
                          fmaxf(wred[2][tid], wred[3][tid]));
    }
    __syncthreads();

    // ---------------- pass 2a: exp(s-m) back into LDS (bf16), row sums
    {
        const int row = tid >> 3;
        const int c8  = (tid & 7) * 8;
        const float m = mrow[row];
        float sum = 0.f;
        for (int i = 0; i < 32; ++i){
            const int col = c8 + i*64;
            s16x8* p = (s16x8*)&sc[row][swz(row, col)];
            s16x8 v = *p;
            s16x8 e;
            #pragma unroll
            for (int j = 0; j < 8; ++j){
                const float ev = __expf(bf2f((unsigned short)v[j]) - m);
                sum += ev;
                e[j] = (short)f2bf(ev);
            }
            *p = e;
        }
        sum += __shfl_xor(sum, 1, 64);
        sum += __shfl_xor(sum, 2, 64);
        sum += __shfl_xor(sum, 4, 64);
        if ((tid & 7) == 0) invl[row] = 1.0f / sum;
    }
    __syncthreads();

    // ---------------- pass 2b-1: normalized score -> global (nontemporal, coalesced)
    {
        float* srow_base = Score + (size_t)bh * S_LEN * S_LEN + (size_t)qbase * S_LEN;
        #pragma unroll 1
        for (int r = 0; r < QBLK; ++r){
            const float iv = invl[r];
            const s16x8 v = *(const s16x8*)&sc[r][swz(r, tid*8)];
            f32x4 o0, o1;
            o0[0]=bf2f((unsigned short)v[0])*iv; o0[1]=bf2f((unsigned short)v[1])*iv;
            o0[2]=bf2f((unsigned short)v[2])*iv; o0[3]=bf2f((unsigned short)v[3])*iv;
            o1[0]=bf2f((unsigned short)v[4])*iv; o1[1]=bf2f((unsigned short)v[5])*iv;
            o1[2]=bf2f((unsigned short)v[6])*iv; o1[3]=bf2f((unsigned short)v[7])*iv;
            f32x4* dst = (f32x4*)(srow_base + (size_t)r * S_LEN + tid*8);
            __builtin_nontemporal_store(o0, dst);
            __builtin_nontemporal_store(o1, dst + 1);
        }
    }

    // ---------------- pass 2b-2: PV with unnormalized exp-P (1/l folded at the end)
    f32x4 oacc[2][4];
    #pragma unroll
    for (int t = 0; t < 2; ++t)
        #pragma unroll
        for (int nt = 0; nt < 4; ++nt)
            oacc[t][nt] = (f32x4){0.f, 0.f, 0.f, 0.f};

    #pragma unroll 2
    for (int c = 0; c < 16; ++c){
        const int kb = cw + c*32;
        // B fragments from V: vf[nt][j] = bf16(V[kb + lg*8 + j][nt*16 + ln])
        s16x8 vf[4];
        #pragma unroll
        for (int j = 0; j < 8; ++j){
            const float* vrow = Vh + (size_t)(kb + lg*8 + j) * D_DIM + ln;
            const float v0 = vrow[0], v1 = vrow[16], v2 = vrow[32], v3 = vrow[48];
            vf[0][j] = (short)f2bf(v0);
            vf[1][j] = (short)f2bf(v1);
            vf[2][j] = (short)f2bf(v2);
            vf[3][j] = (short)f2bf(v3);
        }
        // A fragments (exp-P) from LDS
        s16x8 pa[2];
        #pragma unroll
        for (int t = 0; t < 2; ++t){
            const int row = t*16 + ln;
            pa[t] = *(const s16x8*)&sc[row][swz(row, kb + lg*8)];
        }
        #pragma unroll
        for (int t = 0; t < 2; ++t)
            #pragma unroll
            for (int nt = 0; nt < 4; ++nt)
                oacc[t][nt] = __builtin_amdgcn_mfma_f32_16x16x32_bf16(pa[t], vf[nt], oacc[t][nt], 0, 0, 0);
    }

    // cross-wave reduce of PV partials through LDS (sc is dead now)
    __syncthreads();
    float* red = (float*)&sc[0][0];   // [NWAVE][QBLK][D_DIM] = 32 KB
    #pragma unroll
    for (int t = 0; t < 2; ++t)
        #pragma unroll
        for (int nt = 0; nt < 4; ++nt)
            #pragma unroll
            for (int r = 0; r < 4; ++r){
                const int row = t*16 + lg*4 + r;
                red[((w*QBLK) + row)*D_DIM + nt*16 + ln] = oacc[t][nt][r];
            }
    __syncthreads();
    {
        const int row = tid >> 3;
        const int d8  = (tid & 7) * 8;
        const float iv = invl[row];
        f32x4 s0 = {0.f,0.f,0.f,0.f}, s1 = {0.f,0.f,0.f,0.f};
        #pragma unroll
        for (int ww = 0; ww < NWAVE; ++ww){
            const f32x4* p = (const f32x4*)&red[((ww*QBLK) + row)*D_DIM + d8];
            s0 += p[0]; s1 += p[1];
        }
        s0 *= iv; s1 *= iv;
        f32x4* dst = (f32x4*)(Out + ((size_t)bh * S_LEN + (qbase + row)) * D_DIM + d8);
        __builtin_nontemporal_store(s0, dst);
        __builtin_nontemporal_store(s1, dst + 1);
    }
}

extern "C" void kernel_launch(void* const* d_in, const int* in_sizes, int n_in,
                              void* d_out, int out_size, void* d_ws, size_t ws_size,
                              hipStream_t stream)
{
    const float* q = (const float*)d_in[0];
    const float* k = (const float*)d_in[1];
    const float* v = (const float*)d_in[2];
    float* out   = (float*)d_out;
    float* score = out + (size_t)2 * 16 * S_LEN * D_DIM;   // out is [B,H,S,D] first

    dim3 grid(S_LEN / QBLK, 2 * 16);   // (64 q-tiles, 32 bh)
    sdpa_kernel<<<grid, 256, 0, stream>>>(q, k, v, out, score);
}

// Round 2
// 315.155 us; speedup vs baseline: 1.1322x; 1.1322x over previous
//
#include <hip/hip_runtime.h>
#include <hip/hip_bf16.h>

#define S_LEN 2048
#define D_DIM 64
#define QBLK  32
#define NWAVE 8
#define NTHR  512
#define WCOLS (S_LEN / NWAVE)   // 256 columns per wave

typedef __attribute__((ext_vector_type(4))) float f32x4;
typedef __attribute__((ext_vector_type(8))) short s16x8;
typedef __attribute__((ext_vector_type(2))) unsigned int u32x2;

union FU { float f; unsigned int u; };

__device__ __forceinline__ float bf2f(unsigned short h){
    FU x; x.u = ((unsigned int)h) << 16; return x.f;
}
__device__ __forceinline__ unsigned short f2bf(float f){
    FU x; x.f = f;
    unsigned int r = x.u + 0x7fffu + ((x.u >> 16) & 1u);
    return (unsigned short)(r >> 16);
}

__global__ __launch_bounds__(NTHR, 2)
void sdpa_kernel(const float* __restrict__ Q, const float* __restrict__ K,
                 const float* __restrict__ V, float* __restrict__ Out,
                 float* __restrict__ Score)
{
    // score strip, bf16, XOR-swizzled at 16B-unit granularity: unit U of row r
    // lives at (U ^ (r&7)). 128 KB.
    __shared__ unsigned short sc[QBLK * S_LEN];
    __shared__ float wred[NWAVE][QBLK];
    __shared__ float mrow[QBLK];
    __shared__ float invl[QBLK];

    const int bh    = blockIdx.y;
    const int qbase = blockIdx.x * QBLK;
    const int tid   = threadIdx.x;
    const int w     = tid >> 6;
    const int l     = tid & 63;
    const int lg    = l >> 4;      // lane group 0..3
    const int ln    = l & 15;

    const size_t hbase = (size_t)bh * S_LEN * D_DIM;
    const float* Qh = Q + hbase;
    const float* Kh = K + hbase;
    const float* Vh = V + hbase;

    // ---------------- load Q fragments (scale 1/8 folded in; exact pow2)
    s16x8 qf[2][2];
    #pragma unroll
    for (int t = 0; t < 2; ++t){
        const float* qrow = Qh + (size_t)(qbase + t*16 + ln) * D_DIM;
        #pragma unroll
        for (int s = 0; s < 2; ++s){
            const f32x4* p = (const f32x4*)(qrow + s*32 + lg*8);
            f32x4 a = p[0], b = p[1];
            s16x8 f;
            f[0]=(short)f2bf(a[0]*0.125f); f[1]=(short)f2bf(a[1]*0.125f);
            f[2]=(short)f2bf(a[2]*0.125f); f[3]=(short)f2bf(a[3]*0.125f);
            f[4]=(short)f2bf(b[0]*0.125f); f[5]=(short)f2bf(b[1]*0.125f);
            f[6]=(short)f2bf(b[2]*0.125f); f[7]=(short)f2bf(b[3]*0.125f);
            qf[t][s] = f;
        }
    }

    // ---------------- pass 1: P^T = (K Q^T) via swapped mfma -> packed b64 LDS
    float mloc[2] = { -1e30f, -1e30f };
    const int cw = w * WCOLS;

    #pragma unroll 2
    for (int i = 0; i < 16; ++i){
        const int kb = cw + i*16;
        s16x8 kf[2];
        const float* krow = Kh + (size_t)(kb + ln) * D_DIM;
        #pragma unroll
        for (int s = 0; s < 2; ++s){
            const f32x4* p = (const f32x4*)(krow + s*32 + lg*8);
            f32x4 a = p[0], b = p[1];
            s16x8 f;
            f[0]=(short)f2bf(a[0]); f[1]=(short)f2bf(a[1]); f[2]=(short)f2bf(a[2]); f[3]=(short)f2bf(a[3]);
            f[4]=(short)f2bf(b[0]); f[5]=(short)f2bf(b[1]); f[6]=(short)f2bf(b[2]); f[7]=(short)f2bf(b[3]);
            kf[s] = f;
        }
        #pragma unroll
        for (int t = 0; t < 2; ++t){
            f32x4 acc = {0.f, 0.f, 0.f, 0.f};
            acc = __builtin_amdgcn_mfma_f32_16x16x32_bf16(kf[0], qf[t][0], acc, 0, 0, 0);
            acc = __builtin_amdgcn_mfma_f32_16x16x32_bf16(kf[1], qf[t][1], acc, 0, 0, 0);
            // lane holds P[q = t*16+ln][k = kb + lg*4 + r], r=0..3
            mloc[t] = fmaxf(mloc[t], fmaxf(fmaxf(acc[0], acc[1]), fmaxf(acc[2], acc[3])));
            const unsigned int lo = (unsigned int)f2bf(acc[0]) | ((unsigned int)f2bf(acc[1]) << 16);
            const unsigned int hi = (unsigned int)f2bf(acc[2]) | ((unsigned int)f2bf(acc[3]) << 16);
            const int row = t*16 + ln;
            const int U   = (kb >> 3) + (lg >> 1);
            const int su  = U ^ (row & 7);
            *(u32x2*)&sc[row*S_LEN + su*8 + (lg & 1)*4] = (u32x2){lo, hi};
        }
    }

    // row max: reduce across lg groups (lanes 16 apart share q-row)
    #pragma unroll
    for (int t = 0; t < 2; ++t){
        mloc[t] = fmaxf(mloc[t], __shfl_xor(mloc[t], 16, 64));
        mloc[t] = fmaxf(mloc[t], __shfl_xor(mloc[t], 32, 64));
    }
    if (lg == 0){
        wred[w][ln]      = mloc[0];
        wred[w][16 + ln] = mloc[1];
    }
    __syncthreads();
    if (tid < QBLK){
        float m = wred[0][tid];
        #pragma unroll
        for (int ww = 1; ww < NWAVE; ++ww) m = fmaxf(m, wred[ww][tid]);
        mrow[tid] = m;
    }
    __syncthreads();

    // ---------------- pass 2a: exp(s-m) in place (bf16), row sums
    {
        const int row  = tid >> 4;      // 0..31
        const int part = tid & 15;
        const int rx   = row & 7;
        const float m  = mrow[row];
        float sum = 0.f;
        #pragma unroll 2
        for (int i = 0; i < 16; ++i){
            const int U  = part + i*16;      // 16B unit within row
            const int su = U ^ rx;
            s16x8* p = (s16x8*)&sc[row*S_LEN + su*8];
            s16x8 v = *p;
            s16x8 e;
            #pragma unroll
            for (int j = 0; j < 8; ++j){
                const float ev = __expf(bf2f((unsigned short)v[j]) - m);
                sum += ev;
                e[j] = (short)f2bf(ev);
            }
            *p = e;
        }
        sum += __shfl_xor(sum, 1, 64);
        sum += __shfl_xor(sum, 2, 64);
        sum += __shfl_xor(sum, 4, 64);
        sum += __shfl_xor(sum, 8, 64);
        if (part == 0) invl[row] = 1.0f / sum;
    }
    __syncthreads();

    // ---------------- pass 2b-1: normalized score -> global (nontemporal)
    {
        float* srow_base = Score + (size_t)bh * S_LEN * S_LEN + (size_t)qbase * S_LEN;
        #pragma unroll 1
        for (int rr = 0; rr < QBLK; rr += 2){
            const int row = rr + (tid >> 8);
            const int u   = tid & 255;
            const int su  = u ^ (row & 7);
            const s16x8 v = *(const s16x8*)&sc[row*S_LEN + su*8];
            const float iv = invl[row];
            f32x4 o0, o1;
            o0[0]=bf2f((unsigned short)v[0])*iv; o0[1]=bf2f((unsigned short)v[1])*iv;
            o0[2]=bf2f((unsigned short)v[2])*iv; o0[3]=bf2f((unsigned short)v[3])*iv;
            o1[0]=bf2f((unsigned short)v[4])*iv; o1[1]=bf2f((unsigned short)v[5])*iv;
            o1[2]=bf2f((unsigned short)v[6])*iv; o1[3]=bf2f((unsigned short)v[7])*iv;
            f32x4* dst = (f32x4*)(srow_base + (size_t)row * S_LEN + u*8);
            __builtin_nontemporal_store(o0, dst);
            __builtin_nontemporal_store(o1, dst + 1);
        }
    }

    // ---------------- pass 2b-2: PV with unnormalized exp-P
    f32x4 oacc[2][4];
    #pragma unroll
    for (int t = 0; t < 2; ++t)
        #pragma unroll
        for (int nt = 0; nt < 4; ++nt)
            oacc[t][nt] = (f32x4){0.f, 0.f, 0.f, 0.f};

    #pragma unroll 2
    for (int c = 0; c < 8; ++c){
        const int kb = cw + c*32;
        s16x8 vf[4];
        #pragma unroll
        for (int j = 0; j < 8; ++j){
            const float* vrow = Vh + (size_t)(kb + lg*8 + j) * D_DIM + ln;
            vf[0][j] = (short)f2bf(vrow[0]);
            vf[1][j] = (short)f2bf(vrow[16]);
            vf[2][j] = (short)f2bf(vrow[32]);
            vf[3][j] = (short)f2bf(vrow[48]);
        }
        s16x8 pa[2];
        #pragma unroll
        for (int t = 0; t < 2; ++t){
            const int row = t*16 + ln;
            const int U   = (kb >> 3) + lg;
            const int su  = U ^ (row & 7);
            pa[t] = *(const s16x8*)&sc[row*S_LEN + su*8];
        }
        #pragma unroll
        for (int t = 0; t < 2; ++t)
            #pragma unroll
            for (int nt = 0; nt < 4; ++nt)
                oacc[t][nt] = __builtin_amdgcn_mfma_f32_16x16x32_bf16(pa[t], vf[nt], oacc[t][nt], 0, 0, 0);
    }

    // cross-wave reduce of PV partials through LDS (sc strip is dead now)
    __syncthreads();
    float* red = (float*)&sc[0];   // [NWAVE][QBLK][D_DIM] f32 = 64 KB
    #pragma unroll
    for (int t = 0; t < 2; ++t)
        #pragma unroll
        for (int nt = 0; nt < 4; ++nt)
            #pragma unroll
            for (int r = 0; r < 4; ++r){
                const int row = t*16 + lg*4 + r;
                red[((w*QBLK) + row)*D_DIM + nt*16 + ln] = oacc[t][nt][r];
            }
    __syncthreads();
    {
        const int row = tid >> 4;          // 0..31
        const int d4  = (tid & 15) * 4;    // 16 threads x 4 floats = 64
        const float iv = invl[row];
        f32x4 s = {0.f, 0.f, 0.f, 0.f};
        #pragma unroll
        for (int ww = 0; ww < NWAVE; ++ww)
            s += *(const f32x4*)&red[((ww*QBLK) + row)*D_DIM + d4];
        s *= iv;
        f32x4* dst = (f32x4*)(Out + ((size_t)bh * S_LEN + (qbase + row)) * D_DIM + d4);
        __builtin_nontemporal_store(s, dst);
    }
}

extern "C" void kernel_launch(void* const* d_in, const int* in_sizes, int n_in,
                              void* d_out, int out_size, void* d_ws, size_t ws_size,
                              hipStream_t stream)
{
    const float* q = (const float*)d_in[0];
    const float* k = (const float*)d_in[1];
    const float* v = (const float*)d_in[2];
    float* out   = (float*)d_out;
    float* score = out + (size_t)2 * 16 * S_LEN * D_DIM;   // out is [B,H,S,D] first

    dim3 grid(S_LEN / QBLK, 2 * 16);   // (64 q-tiles, 32 bh)
    sdpa_kernel<<<grid, NTHR, 0, stream>>>(q, k, v, out, score);
}